// Round 1
// baseline (316.166 us; speedup 1.0000x reference)
//
#include <hip/hip_runtime.h>

typedef __attribute__((ext_vector_type(8))) short bf16x8;
typedef __attribute__((ext_vector_type(4))) float f32x4;
typedef __attribute__((ext_vector_type(8))) unsigned short u16x8;
typedef __attribute__((ext_vector_type(4))) unsigned short u16x4;

#define MFMA_16x16x32(a, b, c) __builtin_amdgcn_mfma_f32_16x16x32_bf16((a), (b), (c), 0, 0, 0)

__device__ __forceinline__ unsigned short f2bf(float f) {
  unsigned u = __builtin_bit_cast(unsigned, f);
  u += 0x7fffu + ((u >> 16) & 1u);   // round-to-nearest-even
  return (unsigned short)(u >> 16);
}

__device__ __forceinline__ void gload_lds16(const void* g, void* l) {
  __builtin_amdgcn_global_load_lds((__attribute__((address_space(1))) void*)(g),
                                   (__attribute__((address_space(3))) void*)(l),
                                   16, 0, 0);
}

// ---------------------------------------------------------------- convert ---
__global__ void cvt_bf16(const float* __restrict__ src, unsigned short* __restrict__ dst, int n4) {
  int i = blockIdx.x * blockDim.x + threadIdx.x;
  if (i >= n4) return;
  f32x4 v = *(const f32x4*)(src + (size_t)i * 4);
  u16x4 o;
  o.x = f2bf(v.x); o.y = f2bf(v.y); o.z = f2bf(v.z); o.w = f2bf(v.w);
  *(u16x4*)(dst + (size_t)i * 4) = o;
}

// ------------------------------------------------------------------- GEMM ---
// C[M,N] = A[M,K] * B[N,K]^T   (both row-major, K contiguous). M=4096,N=1024,K=1024.
// OUTMODE 0: bf16 [M][N];  1: bf16 V-transpose -> Vt[((b*16+h)*64+d)*2048 + s];
//         2: fp32 [M][N]
template <int OUTMODE>
__global__ __launch_bounds__(256) void gemm_nt(const unsigned short* __restrict__ A,
                                               const unsigned short* __restrict__ Bw,
                                               void* __restrict__ Cout) {
  constexpr int K = 1024, N = 1024;
  __shared__ unsigned short As[128 * 32];
  __shared__ unsigned short Bs[128 * 32];
  const int tid = threadIdx.x;
  const int lane = tid & 63;
  const int wave = tid >> 6;
  const int wm = (wave >> 1) * 64;
  const int wn = (wave & 1) * 64;
  const int bx = blockIdx.x, by = blockIdx.y;
  const int l15 = lane & 15, lg = lane >> 4;

  f32x4 acc[4][4];
#pragma unroll
  for (int mi = 0; mi < 4; ++mi)
#pragma unroll
    for (int ni = 0; ni < 4; ++ni) acc[mi][ni] = (f32x4){0.f, 0.f, 0.f, 0.f};

  // staging: thread t, op o in {0,1}: lds elem = t*8 + o*2048; row=(t>>2)+o*64; col=(t&3)*8
  const int r0 = tid >> 2;
  const int c0 = (tid & 3) * 8;
  const unsigned short* Ag = A + (size_t)(by * 128 + r0) * K + c0;
  const unsigned short* Bg = Bw + (size_t)(bx * 128 + r0) * K + c0;
  unsigned short* lA = As + tid * 8;
  unsigned short* lB = Bs + tid * 8;

  for (int kt = 0; kt < K / 32; ++kt) {
    __syncthreads();
    gload_lds16(Ag + kt * 32, lA);
    gload_lds16(Ag + (size_t)64 * K + kt * 32, lA + 2048);
    gload_lds16(Bg + kt * 32, lB);
    gload_lds16(Bg + (size_t)64 * K + kt * 32, lB + 2048);
    __syncthreads();

    bf16x8 af[4], bf[4];
#pragma unroll
    for (int mi = 0; mi < 4; ++mi)
      af[mi] = *(const bf16x8*)&As[(wm + mi * 16 + l15) * 32 + lg * 8];
#pragma unroll
    for (int ni = 0; ni < 4; ++ni)
      bf[ni] = *(const bf16x8*)&Bs[(wn + ni * 16 + l15) * 32 + lg * 8];
#pragma unroll
    for (int mi = 0; mi < 4; ++mi)
#pragma unroll
      for (int ni = 0; ni < 4; ++ni)
        acc[mi][ni] = MFMA_16x16x32(af[mi], bf[ni], acc[mi][ni]);
  }

#pragma unroll
  for (int mi = 0; mi < 4; ++mi) {
    const int row = by * 128 + wm + mi * 16 + lg * 4;
#pragma unroll
    for (int ni = 0; ni < 4; ++ni) {
      const int col = bx * 128 + wn + ni * 16 + l15;
#pragma unroll
      for (int i = 0; i < 4; ++i) {
        float v = acc[mi][ni][i];
        if constexpr (OUTMODE == 0) {
          ((unsigned short*)Cout)[(size_t)(row + i) * N + col] = f2bf(v);
        } else if constexpr (OUTMODE == 1) {
          const int m = row + i, n = col;
          ((unsigned short*)Cout)[(size_t)(((m >> 11) * 16 + (n >> 6)) * 64 + (n & 63)) * 2048 +
                                  (m & 2047)] = f2bf(v);
        } else {
          ((float*)Cout)[(size_t)(row + i) * N + col] = v;
        }
      }
    }
  }
}

// -------------------------------------------------------- flash attention ---
// Q,K: [B,S,H,HD] bf16. Vt: [B,H,HD,S] bf16. O: [B,S,H,HD] bf16.
// block: 256 thr, 4 waves; 128 q-rows per block (32/wave); KV tile = 64.
__global__ __launch_bounds__(256) void attn_fwd(const unsigned short* __restrict__ Qg,
                                                const unsigned short* __restrict__ Kg,
                                                const unsigned short* __restrict__ Vtg,
                                                unsigned short* __restrict__ Og) {
  constexpr int S = 2048, D = 1024, HD = 64;
  __shared__ unsigned short Qs[128][72];
  __shared__ unsigned short Ks[64][72];
  __shared__ unsigned short Vts[64][72];
  __shared__ unsigned short Ps[128][72];

  const int tid = threadIdx.x;
  const int lane = tid & 63;
  const int wave = tid >> 6;
  const int l15 = lane & 15;
  const int lg = lane >> 4;
  const int bh = blockIdx.y;
  const int b = bh >> 4, h = bh & 15;
  const int q0 = blockIdx.x * 128;
  const float slope = exp2f(-0.5f * (float)(h + 1));

  {  // Q tile -> LDS
    const int r = tid >> 3;
    const int c = (tid & 7) * 8;
    const unsigned short* src = Qg + (size_t)(b * S + q0 + r) * D + h * HD + c;
#pragma unroll
    for (int o = 0; o < 4; ++o) {
      u16x8 v = *(const u16x8*)(src + (size_t)o * 32 * D);
      *(u16x8*)&Qs[r + o * 32][c] = v;
    }
  }

  f32x4 oc[2][4];
  float m_run[2][4], l_run[2][4];
#pragma unroll
  for (int mi = 0; mi < 2; ++mi)
#pragma unroll
    for (int i = 0; i < 4; ++i) { m_run[mi][i] = -1e30f; l_run[mi][i] = 0.f; }
#pragma unroll
  for (int mi = 0; mi < 2; ++mi)
#pragma unroll
    for (int di = 0; di < 4; ++di) oc[mi][di] = (f32x4){0.f, 0.f, 0.f, 0.f};

  const int ntiles = (q0 + 128) / 64;
  for (int t = 0; t < ntiles; ++t) {
    const int k0 = t * 64;
    __syncthreads();
    {  // stage K and Vt tiles
      const int r = tid >> 3;
      const int c = (tid & 7) * 8;
#pragma unroll
      for (int o = 0; o < 2; ++o) {
        u16x8 kv = *(const u16x8*)(Kg + (size_t)(b * S + k0 + r + o * 32) * D + h * HD + c);
        u16x8 vv = *(const u16x8*)(Vtg + (size_t)(bh * HD + r + o * 32) * S + k0 + c);
        *(u16x8*)&Ks[r + o * 32][c] = kv;
        *(u16x8*)&Vts[r + o * 32][c] = vv;
      }
    }
    __syncthreads();

    // ---- S = Q K^T
    f32x4 sc[2][4];
#pragma unroll
    for (int mi = 0; mi < 2; ++mi)
#pragma unroll
      for (int ni = 0; ni < 4; ++ni) sc[mi][ni] = (f32x4){0.f, 0.f, 0.f, 0.f};
    bf16x8 aq[2][2], bk[4][2];
#pragma unroll
    for (int mi = 0; mi < 2; ++mi)
#pragma unroll
      for (int kk = 0; kk < 2; ++kk)
        aq[mi][kk] = *(const bf16x8*)&Qs[wave * 32 + mi * 16 + l15][kk * 32 + lg * 8];
#pragma unroll
    for (int ni = 0; ni < 4; ++ni)
#pragma unroll
      for (int kk = 0; kk < 2; ++kk)
        bk[ni][kk] = *(const bf16x8*)&Ks[ni * 16 + l15][kk * 32 + lg * 8];
#pragma unroll
    for (int mi = 0; mi < 2; ++mi)
#pragma unroll
      for (int ni = 0; ni < 4; ++ni)
#pragma unroll
        for (int kk = 0; kk < 2; ++kk)
          sc[mi][ni] = MFMA_16x16x32(aq[mi][kk], bk[ni][kk], sc[mi][ni]);

    // ---- bias + causal mask + online softmax (fp32)
#pragma unroll
    for (int mi = 0; mi < 2; ++mi) {
      const int qbase = q0 + wave * 32 + mi * 16 + lg * 4;
#pragma unroll
      for (int i = 0; i < 4; ++i) {
        const int qrow = qbase + i;
        float mx = -1e30f;
#pragma unroll
        for (int ni = 0; ni < 4; ++ni) {
          const int j = k0 + ni * 16 + l15;
          float v = sc[mi][ni][i] * 0.125f + slope * (float)(qrow - j);
          v = (j <= qrow) ? v : -1e30f;
          sc[mi][ni][i] = v;
          mx = fmaxf(mx, v);
        }
        mx = fmaxf(mx, __shfl_xor(mx, 1, 64));
        mx = fmaxf(mx, __shfl_xor(mx, 2, 64));
        mx = fmaxf(mx, __shfl_xor(mx, 4, 64));
        mx = fmaxf(mx, __shfl_xor(mx, 8, 64));
        const float mold = m_run[mi][i];
        const float mnew = fmaxf(mold, mx);
        const float corr = __expf(mold - mnew);
        float rs = 0.f;
#pragma unroll
        for (int ni = 0; ni < 4; ++ni) {
          float p = __expf(sc[mi][ni][i] - mnew);
          sc[mi][ni][i] = p;
          rs += p;
        }
        rs += __shfl_xor(rs, 1, 64);
        rs += __shfl_xor(rs, 2, 64);
        rs += __shfl_xor(rs, 4, 64);
        rs += __shfl_xor(rs, 8, 64);
        l_run[mi][i] = l_run[mi][i] * corr + rs;
        m_run[mi][i] = mnew;
#pragma unroll
        for (int di = 0; di < 4; ++di) oc[mi][di][i] *= corr;
      }
    }

    // ---- P -> LDS (bf16) for the PV A-operand
#pragma unroll
    for (int mi = 0; mi < 2; ++mi)
#pragma unroll
      for (int i = 0; i < 4; ++i)
#pragma unroll
        for (int ni = 0; ni < 4; ++ni)
          Ps[wave * 32 + mi * 16 + lg * 4 + i][ni * 16 + l15] = f2bf(sc[mi][ni][i]);
    __syncthreads();

    // ---- O += P V
    bf16x8 ap[2][2], bv[4][2];
#pragma unroll
    for (int mi = 0; mi < 2; ++mi)
#pragma unroll
      for (int kk = 0; kk < 2; ++kk)
        ap[mi][kk] = *(const bf16x8*)&Ps[wave * 32 + mi * 16 + l15][kk * 32 + lg * 8];
#pragma unroll
    for (int di = 0; di < 4; ++di)
#pragma unroll
      for (int kk = 0; kk < 2; ++kk)
        bv[di][kk] = *(const bf16x8*)&Vts[di * 16 + l15][kk * 32 + lg * 8];
#pragma unroll
    for (int mi = 0; mi < 2; ++mi)
#pragma unroll
      for (int di = 0; di < 4; ++di)
#pragma unroll
        for (int kk = 0; kk < 2; ++kk)
          oc[mi][di] = MFMA_16x16x32(ap[mi][kk], bv[di][kk], oc[mi][di]);
  }

  // ---- normalize + write O
#pragma unroll
  for (int mi = 0; mi < 2; ++mi)
#pragma unroll
    for (int i = 0; i < 4; ++i) {
      const int q = q0 + wave * 32 + mi * 16 + lg * 4 + i;
      const float rcp = 1.0f / l_run[mi][i];
#pragma unroll
      for (int di = 0; di < 4; ++di)
        Og[(size_t)(b * S + q) * D + h * HD + di * 16 + l15] = f2bf(oc[mi][di][i] * rcp);
    }
}

// ----------------------------------------------------------------- launch ---
extern "C" void kernel_launch(void* const* d_in, const int* in_sizes, int n_in,
                              void* d_out, int out_size, void* d_ws, size_t ws_size,
                              hipStream_t stream) {
  const float* x = (const float*)d_in[0];
  const float* Wq = (const float*)d_in[1];
  const float* Wk = (const float*)d_in[2];
  const float* Wv = (const float*)d_in[3];
  const float* Wo = (const float*)d_in[4];

  unsigned short* xb = (unsigned short*)d_ws;          // 4194304
  unsigned short* Wqb = xb + 4194304;                  // 1048576
  unsigned short* Wkb = Wqb + 1048576;
  unsigned short* Wvb = Wkb + 1048576;
  unsigned short* Wob = Wvb + 1048576;
  unsigned short* Qb = Wob + 1048576;                  // 4194304
  unsigned short* Kb = Qb + 4194304;
  unsigned short* Vtb = Kb + 4194304;
  unsigned short* Ob = Vtb + 4194304;                  // total 48 MB

  cvt_bf16<<<4096, 256, 0, stream>>>(x, xb, 1048576);
  cvt_bf16<<<1024, 256, 0, stream>>>(Wq, Wqb, 262144);
  cvt_bf16<<<1024, 256, 0, stream>>>(Wk, Wkb, 262144);
  cvt_bf16<<<1024, 256, 0, stream>>>(Wv, Wvb, 262144);
  cvt_bf16<<<1024, 256, 0, stream>>>(Wo, Wob, 262144);

  gemm_nt<0><<<dim3(8, 32), 256, 0, stream>>>(xb, Wqb, Qb);
  gemm_nt<0><<<dim3(8, 32), 256, 0, stream>>>(xb, Wkb, Kb);
  gemm_nt<1><<<dim3(8, 32), 256, 0, stream>>>(xb, Wvb, Vtb);

  attn_fwd<<<dim3(16, 32), 256, 0, stream>>>(Qb, Kb, Vtb, Ob);

  gemm_nt<2><<<dim3(8, 32), 256, 0, stream>>>(Ob, Wob, (float*)d_out);
}

// Round 7
// 212.022 us; speedup vs baseline: 1.4912x; 1.4912x over previous
//
#include <hip/hip_runtime.h>

typedef __attribute__((ext_vector_type(8))) short bf16x8;
typedef __attribute__((ext_vector_type(4))) float f32x4;
typedef __attribute__((ext_vector_type(16))) float f32x16;
typedef __attribute__((ext_vector_type(8))) unsigned short u16x8;
typedef __attribute__((ext_vector_type(4))) unsigned short u16x4;
typedef __attribute__((ext_vector_type(2))) unsigned int uint2v;

#define MFMA_16x16x32(a, b, c) __builtin_amdgcn_mfma_f32_16x16x32_bf16((a), (b), (c), 0, 0, 0)
#define MFMA32(a, b, c) __builtin_amdgcn_mfma_f32_32x32x16_bf16((a), (b), (c), 0, 0, 0)

__device__ __forceinline__ unsigned short f2bf(float f) {
  unsigned u = __builtin_bit_cast(unsigned, f);
  u += 0x7fffu + ((u >> 16) & 1u);   // round-to-nearest-even
  return (unsigned short)(u >> 16);
}

__device__ __forceinline__ void gload_lds16(const void* g, void* l) {
  __builtin_amdgcn_global_load_lds((__attribute__((address_space(1))) void*)(g),
                                   (__attribute__((address_space(3))) void*)(l),
                                   16, 0, 0);
}

__device__ __forceinline__ unsigned cvtpk(float lo, float hi) {
  unsigned r;
  asm("v_cvt_pk_bf16_f32 %0, %1, %2" : "=v"(r) : "v"(lo), "v"(hi));
  return r;
}

// ---------------------------------------------------------------- convert ---
__global__ void cvt_bf16(const float* __restrict__ src, unsigned short* __restrict__ dst, int n4) {
  int i = blockIdx.x * blockDim.x + threadIdx.x;
  if (i >= n4) return;
  f32x4 v = *(const f32x4*)(src + (size_t)i * 4);
  u16x4 o;
  o.x = f2bf(v.x); o.y = f2bf(v.y); o.z = f2bf(v.z); o.w = f2bf(v.w);
  *(u16x4*)(dst + (size_t)i * 4) = o;
}

// 4 weights in one launch (blockIdx.y selects)
__global__ void cvt_w4(const float* __restrict__ s0, const float* __restrict__ s1,
                       const float* __restrict__ s2, const float* __restrict__ s3,
                       unsigned short* __restrict__ d0, unsigned short* __restrict__ d1,
                       unsigned short* __restrict__ d2, unsigned short* __restrict__ d3,
                       int n4) {
  const float* s; unsigned short* d;
  switch (blockIdx.y) {
    case 0: s = s0; d = d0; break;
    case 1: s = s1; d = d1; break;
    case 2: s = s2; d = d2; break;
    default: s = s3; d = d3; break;
  }
  int i = blockIdx.x * blockDim.x + threadIdx.x;
  if (i >= n4) return;
  f32x4 v = *(const f32x4*)(s + (size_t)i * 4);
  u16x4 o;
  o.x = f2bf(v.x); o.y = f2bf(v.y); o.z = f2bf(v.z); o.w = f2bf(v.w);
  *(u16x4*)(d + (size_t)i * 4) = o;
}

// ------------------------------------------------------------------- GEMM ---
// C[M,N] = A[M,K] * B[N,K]^T, M=4096, N=K=1024.
// outmode 0: bf16 [M][N] scaled; 1: bf16 V-transpose Vt[(bh*64+d)*2048+s]; 2: fp32
template <int OUTMODE>
__device__ __forceinline__ void gemm_body(const unsigned short* __restrict__ A,
                                          const unsigned short* __restrict__ Bw,
                                          void* __restrict__ Cout, float scale,
                                          int bx, int by) {
  constexpr int K = 1024, N = 1024;
  __shared__ unsigned short As[128 * 32];
  __shared__ unsigned short Bs[128 * 32];
  const int tid = threadIdx.x;
  const int lane = tid & 63;
  const int wave = tid >> 6;
  const int wm = (wave >> 1) * 64;
  const int wn = (wave & 1) * 64;
  const int l15 = lane & 15, lg = lane >> 4;

  f32x4 acc[4][4];
#pragma unroll
  for (int mi = 0; mi < 4; ++mi)
#pragma unroll
    for (int ni = 0; ni < 4; ++ni) acc[mi][ni] = (f32x4){0.f, 0.f, 0.f, 0.f};

  const int r0 = tid >> 2;
  const int c0 = (tid & 3) * 8;
  const unsigned short* Ag = A + (size_t)(by * 128 + r0) * K + c0;
  const unsigned short* Bg = Bw + (size_t)(bx * 128 + r0) * K + c0;
  unsigned short* lA = As + tid * 8;
  unsigned short* lB = Bs + tid * 8;

  for (int kt = 0; kt < K / 32; ++kt) {
    __syncthreads();
    gload_lds16(Ag + kt * 32, lA);
    gload_lds16(Ag + (size_t)64 * K + kt * 32, lA + 2048);
    gload_lds16(Bg + kt * 32, lB);
    gload_lds16(Bg + (size_t)64 * K + kt * 32, lB + 2048);
    __syncthreads();

    bf16x8 af[4], bf[4];
#pragma unroll
    for (int mi = 0; mi < 4; ++mi)
      af[mi] = *(const bf16x8*)&As[(wm + mi * 16 + l15) * 32 + lg * 8];
#pragma unroll
    for (int ni = 0; ni < 4; ++ni)
      bf[ni] = *(const bf16x8*)&Bs[(wn + ni * 16 + l15) * 32 + lg * 8];
#pragma unroll
    for (int mi = 0; mi < 4; ++mi)
#pragma unroll
      for (int ni = 0; ni < 4; ++ni)
        acc[mi][ni] = MFMA_16x16x32(af[mi], bf[ni], acc[mi][ni]);
  }

#pragma unroll
  for (int mi = 0; mi < 4; ++mi) {
    const int row = by * 128 + wm + mi * 16 + lg * 4;
#pragma unroll
    for (int ni = 0; ni < 4; ++ni) {
      const int col = bx * 128 + wn + ni * 16 + l15;
#pragma unroll
      for (int i = 0; i < 4; ++i) {
        float v = acc[mi][ni][i];
        if constexpr (OUTMODE == 0) {
          ((unsigned short*)Cout)[(size_t)(row + i) * N + col] = f2bf(v * scale);
        } else if constexpr (OUTMODE == 1) {
          const int m = row + i, n = col;
          ((unsigned short*)Cout)[(size_t)(((m >> 11) * 16 + (n >> 6)) * 64 + (n & 63)) * 2048 +
                                  (m & 2047)] = f2bf(v);
        } else {
          ((float*)Cout)[(size_t)(row + i) * N + col] = v;
        }
      }
    }
  }
}

// fused QKV: grid (8, 32, 3); z=0 -> Q (scaled by log2e/8), z=1 -> K, z=2 -> Vt
__global__ __launch_bounds__(256) void gemm_qkv(const unsigned short* __restrict__ A,
                                                const unsigned short* __restrict__ Wq,
                                                const unsigned short* __restrict__ Wk,
                                                const unsigned short* __restrict__ Wv,
                                                unsigned short* __restrict__ Qo,
                                                unsigned short* __restrict__ Ko,
                                                unsigned short* __restrict__ Vo) {
  const int z = blockIdx.z;
  if (z == 0)      gemm_body<0>(A, Wq, Qo, 0.18033688011112042f, blockIdx.x, blockIdx.y);
  else if (z == 1) gemm_body<0>(A, Wk, Ko, 1.0f, blockIdx.x, blockIdx.y);
  else             gemm_body<1>(A, Wv, Vo, 1.0f, blockIdx.x, blockIdx.y);
}

__global__ __launch_bounds__(256) void gemm_out(const unsigned short* __restrict__ A,
                                                const unsigned short* __restrict__ Bw,
                                                float* __restrict__ C) {
  gemm_body<2>(A, Bw, C, 1.0f, blockIdx.x, blockIdx.y);
}

// -------------------------------------------------------- flash attention ---
// Q,K: [B,S,H*HD] bf16 (Q pre-scaled by log2e/8). Vt: [B,H,HD,S] bf16.
// O: [B,S,H*HD] bf16. No LDS, no barriers; 1 wave owns 32 q-rows.
// Swapped-operand: S^T = mfma(K_frag, Q_frag); lane owns q = lane&31.
// Cross-half exchange via __shfl_xor(...,32) — ISA-unambiguous semantics.
__global__ __launch_bounds__(256, 2) void attn_fwd(const unsigned short* __restrict__ Qg,
                                                   const unsigned short* __restrict__ Kg,
                                                   const unsigned short* __restrict__ Vtg,
                                                   unsigned short* __restrict__ Og) {
  constexpr int S = 2048;
  // swizzle: each head pinned to one XCD (KV 1MB < 4MB L2); pair x with 15-x for balance
  const int bid = blockIdx.x;          // [0, 512)
  const int xcd = bid & 7;
  const int ii = bid >> 3;             // [0, 64)
  const int hi2 = ii >> 5;             // 0/1
  const int jj = ii & 31;
  const int x = hi2 ? (15 - (jj & 15)) : (jj & 15);
  const int bh = xcd * 4 + hi2 * 2 + (jj >> 4);
  const int b = bh >> 4, h = bh & 15;

  const int lane = threadIdx.x & 63;
  const int wave = threadIdx.x >> 6;
  const int ql = lane & 31;
  const int H = lane >> 5;
  const int qw0 = x * 128 + wave * 32;
  const int qg = qw0 + ql;                       // q-row owned by this lane
  const float slope = exp2f(-0.5f * (float)(h + 1));
  const float sl2 = slope * 1.44269504088896f;   // slope * log2(e)

  // Q fragments (B-operand: lane holds col q=lane&31, d = 16c + 8H + j)
  bf16x8 qf[4];
  {
    const unsigned short* qp = Qg + (size_t)(b * S + qg) * 1024 + h * 64 + H * 8;
#pragma unroll
    for (int c = 0; c < 4; ++c) qf[c] = *(const bf16x8*)(qp + 16 * c);
  }

  // -bias table used as MFMA C-init: nbj[r] = -sl2 * (crow(r) + 4H)
  f32x16 nbj;
#pragma unroll
  for (int r = 0; r < 16; ++r) {
    const float crow = (float)((r & 3) + 8 * (r >> 2) + 4 * H);
    nbj[r] = -sl2 * crow;
  }

  // K rows k_local = lane&31 (+32 for subtile 1); row stride 1024 elems
  const unsigned short* kp0 = Kg + (size_t)(b * S + ql) * 1024 + h * 64 + H * 8;
  const unsigned short* kp1 = kp0 + (size_t)32 * 1024;
  // Vt rows d = lane&31 (+32); row stride S elems
  const unsigned short* vp0 = Vtg + (size_t)(bh * 64 + ql) * S + H * 8;
  const unsigned short* vp1 = vp0 + (size_t)32 * S;

  f32x16 o0, o1;
#pragma unroll
  for (int r = 0; r < 16; ++r) { o0[r] = 0.f; o1[r] = 0.f; }
  float m = -1e30f, l = 0.f;

  const int nt = ((qw0 + 31) >> 6) + 1;   // exactly 1 masked (diagonal) tile: the last
  for (int t = 0; t < nt; ++t) {
    const int k0 = t * 64;
    bf16x8 kf0[4], kf1[4], vf0[4], vf1[4];
#pragma unroll
    for (int c = 0; c < 4; ++c) {
      kf0[c] = *(const bf16x8*)(kp0 + 16 * c);
      kf1[c] = *(const bf16x8*)(kp1 + 16 * c);
      vf0[c] = *(const bf16x8*)(vp0 + 16 * c);
      vf1[c] = *(const bf16x8*)(vp1 + 16 * c);
    }
    kp0 += 65536; kp1 += 65536; vp0 += 64; vp1 += 64;

    // S^T = K * Q^T with C-init = -bias (crow part); uniform part folded below
    f32x16 s0 = MFMA32(kf0[0], qf[0], nbj);
    f32x16 s1 = MFMA32(kf1[0], qf[0], nbj);
#pragma unroll
    for (int c = 1; c < 4; ++c) {
      s0 = MFMA32(kf0[c], qf[c], s0);
      s1 = MFMA32(kf1[c], qf[c], s1);
    }

    if (t == nt - 1) {  // causal mask, diagonal tile only (wave-uniform branch)
      const int qk = qg - k0 - 4 * H;
#pragma unroll
      for (int r = 0; r < 16; ++r) {
        const int crow = (r & 3) + 8 * (r >> 2);
        s0[r] = (crow > qk) ? -1e30f : s0[r];
        s1[r] = (crow + 32 > qk) ? -1e30f : s1[r];
      }
    }

    const float vb0 = sl2 * (float)k0;          // uniform bias part, subtile 0
    const float vb1 = sl2 * (float)(k0 + 32);
    // row max (in-lane tree + cross-half merge)
    float mx0 = s0[0], mx1 = s1[0];
#pragma unroll
    for (int r = 1; r < 16; ++r) { mx0 = fmaxf(mx0, s0[r]); mx1 = fmaxf(mx1, s1[r]); }
    float tmax = fmaxf(mx0 - vb0, mx1 - vb1);
    tmax = fmaxf(tmax, __shfl_xor(tmax, 32, 64));
    const float mnew = fmaxf(m, tmax);
    const float corr = __builtin_amdgcn_exp2f(m - mnew);
    m = mnew;
    const float e0 = vb0 + mnew, e1 = vb1 + mnew;

    f32x16 pp0, pp1;
#pragma unroll
    for (int r = 0; r < 16; ++r) {
      pp0[r] = __builtin_amdgcn_exp2f(s0[r] - e0);
      pp1[r] = __builtin_amdgcn_exp2f(s1[r] - e1);
    }
    // row sum (tree) + cross-half merge
    float t8[8];
#pragma unroll
    for (int r = 0; r < 8; ++r) t8[r] = (pp0[r] + pp0[r + 8]) + (pp1[r] + pp1[r + 8]);
    float tsum = ((t8[0] + t8[1]) + (t8[2] + t8[3])) + ((t8[4] + t8[5]) + (t8[6] + t8[7]));
    tsum += __shfl_xor(tsum, 32, 64);
    l = l * corr + tsum;

#pragma unroll
    for (int r = 0; r < 16; ++r) { o0[r] *= corr; o1[r] *= corr; }

    // pack P -> bf16 B-operand fragments and accumulate PV (O^T += V^T * P^T)
    // own words per ck: w0={r0,r1} w1={r2,r3} w2={r4,r5} w3={r6,r7} (+8(ck&1), pp0/pp1 by ck>>1)
    // slot needs (lane H): j0..3 -> k=16ck+8H+{0..3}; j4..7 -> k=16ck+8H+{4..7}.
    // H=0 own rows give k{0..3}+{8..11}; partner(H=1) rows give k{4..7}+{12..15}.
    //  -> H=0 fragment = {w0, w1, partner w0, partner w1}
    //  -> H=1 fragment = {partner w2, partner w3, w2, w3}
#pragma unroll
    for (int ck = 0; ck < 4; ++ck) {
      const int c = ck & 1;
      unsigned w0, w1, w2, w3;
      if (ck < 2) {
        w0 = cvtpk(pp0[8 * c + 0], pp0[8 * c + 1]);
        w1 = cvtpk(pp0[8 * c + 2], pp0[8 * c + 3]);
        w2 = cvtpk(pp0[8 * c + 4], pp0[8 * c + 5]);
        w3 = cvtpk(pp0[8 * c + 6], pp0[8 * c + 7]);
      } else {
        w0 = cvtpk(pp1[8 * c + 0], pp1[8 * c + 1]);
        w1 = cvtpk(pp1[8 * c + 2], pp1[8 * c + 3]);
        w2 = cvtpk(pp1[8 * c + 4], pp1[8 * c + 5]);
        w3 = cvtpk(pp1[8 * c + 6], pp1[8 * c + 7]);
      }
      // H=0 lanes send w2,w3 (their r4..7 = partner's needed k8..11);
      // H=1 lanes send w0,w1 (their r0..3 = partner's needed k4..7).
      unsigned sa = H ? w0 : w2;
      unsigned sb = H ? w1 : w3;
      sa = (unsigned)__shfl_xor((int)sa, 32, 64);
      sb = (unsigned)__shfl_xor((int)sb, 32, 64);
      union { unsigned u[4]; bf16x8 v; } fr;
      fr.u[0] = H ? sa : w0;
      fr.u[1] = H ? sb : w1;
      fr.u[2] = H ? w2 : sa;
      fr.u[3] = H ? w3 : sb;
      o0 = MFMA32(vf0[ck], fr.v, o0);
      o1 = MFMA32(vf1[ck], fr.v, o1);
    }
  }

  // epilogue: O^T regs -> O[b][q][h*64 + d], d = 32*dsub + 8a + 4H + {0..3}
  const float rl = __builtin_amdgcn_rcpf(l);
  unsigned short* ob = Og + (size_t)(b * S + qg) * 1024 + h * 64 + 4 * H;
#pragma unroll
  for (int a2 = 0; a2 < 4; ++a2) {
    uint2v w01, w23;
    w01.x = cvtpk(o0[4 * a2 + 0] * rl, o0[4 * a2 + 1] * rl);
    w01.y = cvtpk(o0[4 * a2 + 2] * rl, o0[4 * a2 + 3] * rl);
    w23.x = cvtpk(o1[4 * a2 + 0] * rl, o1[4 * a2 + 1] * rl);
    w23.y = cvtpk(o1[4 * a2 + 2] * rl, o1[4 * a2 + 3] * rl);
    *(uint2v*)(ob + 8 * a2) = w01;
    *(uint2v*)(ob + 32 + 8 * a2) = w23;
  }
}

// ----------------------------------------------------------------- launch ---
extern "C" void kernel_launch(void* const* d_in, const int* in_sizes, int n_in,
                              void* d_out, int out_size, void* d_ws, size_t ws_size,
                              hipStream_t stream) {
  const float* x = (const float*)d_in[0];
  const float* Wq = (const float*)d_in[1];
  const float* Wk = (const float*)d_in[2];
  const float* Wv = (const float*)d_in[3];
  const float* Wo = (const float*)d_in[4];

  unsigned short* xb = (unsigned short*)d_ws;          // 4194304
  unsigned short* Wqb = xb + 4194304;                  // 1048576 each
  unsigned short* Wkb = Wqb + 1048576;
  unsigned short* Wvb = Wkb + 1048576;
  unsigned short* Wob = Wvb + 1048576;
  unsigned short* Qb = Wob + 1048576;                  // 4194304 each
  unsigned short* Kb = Qb + 4194304;
  unsigned short* Vtb = Kb + 4194304;
  unsigned short* Ob = Vtb + 4194304;

  cvt_bf16<<<4096, 256, 0, stream>>>(x, xb, 1048576);
  cvt_w4<<<dim3(1024, 4), 256, 0, stream>>>(Wq, Wk, Wv, Wo, Wqb, Wkb, Wvb, Wob, 262144);

  gemm_qkv<<<dim3(8, 32, 3), 256, 0, stream>>>(xb, Wqb, Wkb, Wvb, Qb, Kb, Vtb);

  attn_fwd<<<512, 256, 0, stream>>>(Qb, Kb, Vtb, Ob);

  gemm_out<<<dim3(8, 32), 256, 0, stream>>>(Ob, Wob, (float*)d_out);
}